// Round 1
// baseline (79.308 us; speedup 1.0000x reference)
//
#include <hip/hip_runtime.h>

#define NSAMP 2097152
#define NCLS  16
#define DECAY 0.8f

// ---------------------------------------------------------------------------
// Kernel 1: 16-bin histogram of targets. int4-vectorized, LDS bins.
// ---------------------------------------------------------------------------
__global__ void dwce_hist_kernel(const int4* __restrict__ targets4,
                                 unsigned int* __restrict__ counts, int n4) {
    __shared__ unsigned int lhist[NCLS];
    const int tid = threadIdx.x;
    if (tid < NCLS) lhist[tid] = 0u;
    __syncthreads();

    const int stride = gridDim.x * blockDim.x;
    for (int i = blockIdx.x * blockDim.x + tid; i < n4; i += stride) {
        int4 t = targets4[i];
        atomicAdd(&lhist[t.x], 1u);
        atomicAdd(&lhist[t.y], 1u);
        atomicAdd(&lhist[t.z], 1u);
        atomicAdd(&lhist[t.w], 1u);
    }
    __syncthreads();
    if (tid < NCLS) atomicAdd(&counts[tid], lhist[tid]);
}

// ---------------------------------------------------------------------------
// Kernel 2: weighted cross-entropy partial sums.
//   Per block: compute EMA weight w[16] from counts (thread 0, trivial),
//   then grid-stride over samples. Row of 16 logits loaded as 4x float4,
//   log-softmax fully in registers (no runtime-indexed array -> no scratch).
//   Block-reduce in double, one atomicAdd pair per block.
// ---------------------------------------------------------------------------
__global__ void dwce_main_kernel(const float* __restrict__ logits,
                                 const int*   __restrict__ targets,
                                 const float* __restrict__ weight,
                                 const unsigned int* __restrict__ counts,
                                 double* __restrict__ sums, int n) {
    __shared__ float w[NCLS];
    if (threadIdx.x == 0) {
        float raw[NCLS];
        float s = 0.f;
        #pragma unroll
        for (int c = 0; c < NCLS; ++c) {
            raw[c] = (float)NSAMP / (float)counts[c];
            s += raw[c];
        }
        #pragma unroll
        for (int c = 0; c < NCLS; ++c) {
            w[c] = DECAY * weight[c] + (1.0f - DECAY) * (raw[c] / s);
        }
    }
    __syncthreads();

    float accA = 0.f;   // sum(w[t] * nll)
    float accB = 0.f;   // sum(w[t])
    const int stride = gridDim.x * blockDim.x;
    for (int i = blockIdx.x * blockDim.x + threadIdx.x; i < n; i += stride) {
        const float4* row = (const float4*)(logits + (size_t)i * NCLS);
        float4 r0 = row[0];
        float4 r1 = row[1];
        float4 r2 = row[2];
        float4 r3 = row[3];
        float x[NCLS] = {r0.x, r0.y, r0.z, r0.w,
                         r1.x, r1.y, r1.z, r1.w,
                         r2.x, r2.y, r2.z, r2.w,
                         r3.x, r3.y, r3.z, r3.w};
        const int t = targets[i];

        float m = x[0];
        #pragma unroll
        for (int j = 1; j < NCLS; ++j) m = fmaxf(m, x[j]);

        float se = 0.f;
        float xt = 0.f;
        #pragma unroll
        for (int j = 0; j < NCLS; ++j) {
            se += __expf(x[j] - m);
            xt = (j == t) ? x[j] : xt;   // register cndmask chain, no scratch
        }
        const float nll = __logf(se) - (xt - m);
        const float sw = w[t];
        accA += sw * nll;
        accB += sw;
    }

    // wave reduce (64 lanes) in double
    double dA = (double)accA;
    double dB = (double)accB;
    #pragma unroll
    for (int off = 32; off > 0; off >>= 1) {
        dA += __shfl_down(dA, off);
        dB += __shfl_down(dB, off);
    }
    __shared__ double sA[4], sB[4];  // 256 threads = 4 waves
    const int wid  = threadIdx.x >> 6;
    const int lane = threadIdx.x & 63;
    if (lane == 0) { sA[wid] = dA; sB[wid] = dB; }
    __syncthreads();
    if (threadIdx.x == 0) {
        double a = sA[0] + sA[1] + sA[2] + sA[3];
        double b = sB[0] + sB[1] + sB[2] + sB[3];
        atomicAdd(&sums[0], a);
        atomicAdd(&sums[1], b);
    }
}

// ---------------------------------------------------------------------------
// Kernel 3: finalize scalar.
// ---------------------------------------------------------------------------
__global__ void dwce_final_kernel(const double* __restrict__ sums,
                                  float* __restrict__ out) {
    out[0] = (float)(sums[0] / sums[1]);
}

extern "C" void kernel_launch(void* const* d_in, const int* in_sizes, int n_in,
                              void* d_out, int out_size, void* d_ws, size_t ws_size,
                              hipStream_t stream) {
    const float* logits  = (const float*)d_in[0];
    const int*   targets = (const int*)d_in[1];
    const float* weight  = (const float*)d_in[2];
    float* out = (float*)d_out;

    unsigned int* counts = (unsigned int*)d_ws;                 // 16 * 4 = 64 B
    double*       sums   = (double*)((char*)d_ws + 64);         // 2 * 8  = 16 B

    const int n = in_sizes[1];  // N samples (targets flat count)

    // d_ws is poisoned 0xAA once and never re-poisoned -> zero what we use.
    hipMemsetAsync(d_ws, 0, 128, stream);

    dwce_hist_kernel<<<512, 256, 0, stream>>>((const int4*)targets, counts, n / 4);
    dwce_main_kernel<<<2048, 256, 0, stream>>>(logits, targets, weight, counts, sums, n);
    dwce_final_kernel<<<1, 1, 0, stream>>>(sums, out);
}